// Round 1
// baseline (1817.670 us; speedup 1.0000x reference)
//
#include <hip/hip_runtime.h>
#include <hip/hip_bf16.h>
#include <cstdint>
#include <cstddef>

#define NUSERS 200000
#define NITEMS 100000
#define UDIM 64
#define HID 128
#define ODIM 64
#define NREL 5

static inline size_t align256(size_t x){ return (x + 255) & ~(size_t)255; }
static inline int imin(int a,int b){ return a<b?a:b; }

// ---------------- CSR build ----------------

__global__ void count_edges_k(const int* __restrict__ src, const int* __restrict__ dst,
                              const int* __restrict__ et, int E,
                              int* __restrict__ cnt_item, int* __restrict__ cnt_user){
  int e = blockIdx.x*blockDim.x + threadIdx.x;
  if(e < E){
    int t = et[e];
    atomicAdd(&cnt_item[dst[e]*NREL + t], 1);
    atomicAdd(&cnt_user[src[e]*NREL + t], 1);
  }
}

// per-block (1024 elems) totals of deg(i) = sum_r cnt5[i*5+r]
__global__ __launch_bounds__(256) void scan_s1(const int* __restrict__ cnt5, int n, int* __restrict__ btot){
  int t = threadIdx.x;
  int base = blockIdx.x*1024 + t*4;
  int s = 0;
  #pragma unroll
  for(int j=0;j<4;++j){
    int i = base + j;
    if(i < n){ const int* c = &cnt5[i*NREL]; s += c[0]+c[1]+c[2]+c[3]+c[4]; }
  }
  __shared__ int red[256];
  red[t] = s; __syncthreads();
  for(int o=128;o>0;o>>=1){ if(t<o) red[t]+=red[t+o]; __syncthreads(); }
  if(t==0) btot[blockIdx.x] = red[0];
}

// single block: exclusive scan of block totals (nb <= 1024), also writes grand total
__global__ __launch_bounds__(1024) void scan_s2(const int* __restrict__ btot, int nb,
                                                int* __restrict__ boff, int* __restrict__ total_out){
  __shared__ int sh[1024];
  int t = threadIdx.x;
  int v = (t<nb)? btot[t] : 0;
  sh[t] = v; __syncthreads();
  for(int o=1;o<1024;o<<=1){
    int add = (t>=o)? sh[t-o] : 0;
    __syncthreads();
    sh[t] += add;
    __syncthreads();
  }
  if(t<nb) boff[t] = sh[t]-v;
  if(t==1023) *total_out = sh[1023];
}

__global__ __launch_bounds__(256) void scan_s3(const int* __restrict__ cnt5, int n,
                                               const int* __restrict__ boff, int* __restrict__ off){
  int t = threadIdx.x, b = blockIdx.x;
  int base = b*1024 + t*4;
  int pre[4]; int s = 0;
  #pragma unroll
  for(int j=0;j<4;++j){
    int i = base + j; int d = 0;
    if(i < n){ const int* c = &cnt5[i*NREL]; d = c[0]+c[1]+c[2]+c[3]+c[4]; }
    pre[j] = s; s += d;
  }
  __shared__ int sh[256];
  sh[t] = s; __syncthreads();
  int inc = s;
  for(int o=1;o<256;o<<=1){
    int add = (t>=o)? sh[t-o] : 0;
    __syncthreads();
    sh[t] += add;
    __syncthreads();
  }
  int texcl = sh[t] - inc;
  int bo = boff[b];
  #pragma unroll
  for(int j=0;j<4;++j){
    int i = base + j;
    if(i < n) off[i] = bo + texcl + pre[j];
  }
}

__global__ void copy_int_k(const int* __restrict__ a, int* __restrict__ b, int n){
  int i = blockIdx.x*blockDim.x + threadIdx.x;
  if(i < n) b[i] = a[i];
}

__global__ void scatter_k(const int* __restrict__ src, const int* __restrict__ dst,
                          const int* __restrict__ et, int E,
                          int* __restrict__ cur_item, int* __restrict__ cur_user,
                          int* __restrict__ adj_item, int* __restrict__ adj_user){
  int e = blockIdx.x*blockDim.x + threadIdx.x;
  if(e < E){
    int s = src[e], d = dst[e], t = et[e];
    int p1 = atomicAdd(&cur_item[d], 1);
    adj_item[p1] = (s<<3) | t;
    int p2 = atomicAdd(&cur_user[s], 1);
    adj_user[p2] = (d<<3) | t;
  }
}

// ---------------- aggregation: one wave per destination node ----------------
// writes M row = [mean_r0 | mean_r1 | ... | mean_r4], each D wide (already /cnt)

template<int D>
__global__ __launch_bounds__(256) void agg_k(const float* __restrict__ x, const int* __restrict__ adj,
                                             const int* __restrict__ off, const int* __restrict__ cnt5,
                                             float* __restrict__ Mbuf, int lo, int cn){
  int wid  = (int)((blockIdx.x*(size_t)blockDim.x + threadIdx.x) >> 6);
  int lane = threadIdx.x & 63;
  if(wid >= cn) return;
  int node = lo + wid;
  int e0 = off[node], e1 = off[node+1];
  constexpr int V = D/64;
  float sum[NREL][V];
  #pragma unroll
  for(int r=0;r<NREL;++r)
    #pragma unroll
    for(int v=0;v<V;++v) sum[r][v] = 0.f;
  for(int e=e0; e<e1; ++e){
    int a = adj[e];
    int p = a >> 3, t = a & 7;
    const float* xp = x + (size_t)p*D;
    float v0 = xp[lane];
    float v1 = (V==2)? xp[64+lane] : 0.f;
    #pragma unroll
    for(int r=0;r<NREL;++r){
      if(t==r){ sum[r][0] += v0; if(V==2) sum[r][1] += v1; }
    }
  }
  float* outp = Mbuf + (size_t)wid*(NREL*D);
  #pragma unroll
  for(int r=0;r<NREL;++r){
    int c = cnt5[node*NREL + r];
    float sc = 1.f/(float)(c>0?c:1);
    outp[r*D + lane] = sum[r][0]*sc;
    if(V==2) outp[r*D + 64 + lane] = sum[r][1]*sc;
  }
}

// ---------------- fp32 tiled GEMM:  C[MxBN] (+)= A[MxK] @ B[KxBN]  ----------------
// INIT: C = bias + A@B ; else C += A@B.  grid.x = ceil(M/64); N == BN exactly.

template<int BN, int TN, bool INIT>
__global__ __launch_bounds__(256) void gemm_k(const float* __restrict__ A, int lda,
                                              const float* __restrict__ B,
                                              float* __restrict__ C, int ldc,
                                              const float* __restrict__ bias,
                                              int M, int K){
  constexpr int BM = 64, BK = 32, TM = 4;
  __shared__ float As[BK][BM+1];
  __shared__ float Bs[BK][BN];
  const int tid = threadIdx.x;
  const int tx = tid & 15;
  const int ty = tid >> 4;
  const int row0 = blockIdx.x * BM;
  float acc[TM][TN];
  #pragma unroll
  for(int i=0;i<TM;++i)
    #pragma unroll
    for(int j=0;j<TN;++j) acc[i][j] = 0.f;

  for(int k0=0; k0<K; k0+=BK){
    // A tile (BM x BK), store transposed
    #pragma unroll
    for(int jj=0;jj<2;++jj){
      int l = tid + jj*256;          // float4 slot 0..511
      int r = l >> 3;                // 8 float4 per row
      int c4 = (l & 7) << 2;
      float4 v = {0.f,0.f,0.f,0.f};
      int grow = row0 + r;
      if(grow < M) v = *reinterpret_cast<const float4*>(A + (size_t)grow*lda + (k0 + c4));
      As[c4+0][r]=v.x; As[c4+1][r]=v.y; As[c4+2][r]=v.z; As[c4+3][r]=v.w;
    }
    // B tile (BK x BN), row-major direct
    constexpr int BF4 = (BK*BN/4)/256;
    #pragma unroll
    for(int jj=0;jj<BF4;++jj){
      int l = tid + jj*256;
      int r = l / (BN/4);
      int c4 = (l % (BN/4)) << 2;
      *reinterpret_cast<float4*>(&Bs[r][c4]) =
        *reinterpret_cast<const float4*>(B + (size_t)(k0+r)*BN + c4);
    }
    __syncthreads();
    #pragma unroll
    for(int kk=0;kk<BK;++kk){
      float a[TM], b[TN];
      #pragma unroll
      for(int i=0;i<TM;++i) a[i] = As[kk][ty*TM+i];
      #pragma unroll
      for(int j=0;j<TN;++j) b[j] = Bs[kk][tx*TN+j];
      #pragma unroll
      for(int i=0;i<TM;++i)
        #pragma unroll
        for(int j=0;j<TN;++j) acc[i][j] += a[i]*b[j];
    }
    __syncthreads();
  }
  #pragma unroll
  for(int i=0;i<TM;++i){
    int grow = row0 + ty*TM + i;
    if(grow >= M) continue;
    float* cp = C + (size_t)grow*ldc + tx*TN;
    #pragma unroll
    for(int j=0;j<TN;++j){
      float v = acc[i][j];
      if(INIT) v += bias[tx*TN+j];
      else     v += cp[j];
      cp[j] = v;
    }
  }
}

__global__ void relu_k(float* __restrict__ p, size_t n){
  size_t i = (size_t)blockIdx.x*blockDim.x + threadIdx.x;
  size_t stride = (size_t)gridDim.x*blockDim.x;
  for(; i<n; i+=stride) p[i] = fmaxf(p[i], 0.f);
}

// ---------------- host ----------------

extern "C" void kernel_launch(void* const* d_in, const int* in_sizes, int n_in,
                              void* d_out, int out_size, void* d_ws, size_t ws_size,
                              hipStream_t stream){
  const float* x_user   = (const float*)d_in[0];
  const float* x_item   = (const float*)d_in[1];
  const int*   ei       = (const int*)d_in[2];
  const int*   et       = (const int*)d_in[3];
  const float* W1_ui    = (const float*)d_in[4];
  const float* root1_ui = (const float*)d_in[5];
  const float* b1_ui    = (const float*)d_in[6];
  const float* W1_iu    = (const float*)d_in[7];
  const float* root1_iu = (const float*)d_in[8];
  const float* b1_iu    = (const float*)d_in[9];
  const float* W2_ui    = (const float*)d_in[10];
  const float* root2_ui = (const float*)d_in[11];
  const float* b2_ui    = (const float*)d_in[12];
  const float* W2_iu    = (const float*)d_in[13];
  const float* root2_iu = (const float*)d_in[14];
  const float* b2_iu    = (const float*)d_in[15];
  const int E = in_sizes[3];
  const int* src = ei;
  const int* dst = ei + E;
  float* out = (float*)d_out;

  uint8_t* ws = (uint8_t*)d_ws;
  size_t o = 0;
  auto alloc = [&](size_t bytes){ size_t r = o; o = align256(o + bytes); return r; };
  int* cnt_item = (int*)(ws + alloc((size_t)NITEMS*NREL*4));
  int* cnt_user = (int*)(ws + alloc((size_t)NUSERS*NREL*4));
  int* off_item = (int*)(ws + alloc((size_t)(NITEMS+1)*4));
  int* off_user = (int*)(ws + alloc((size_t)(NUSERS+1)*4));
  int* cur_item = (int*)(ws + alloc((size_t)NITEMS*4));
  int* cur_user = (int*)(ws + alloc((size_t)NUSERS*4));
  int* adj_item = (int*)(ws + alloc((size_t)E*4));
  int* adj_user = (int*)(ws + alloc((size_t)E*4));
  int* btot     = (int*)(ws + alloc(1024*4));
  int* boff     = (int*)(ws + alloc(1024*4));
  float* user1  = (float*)(ws + alloc((size_t)NUSERS*HID*4));
  float* item1  = (float*)(ws + alloc((size_t)NITEMS*HID*4));
  size_t moff = o;
  size_t avail = (ws_size > moff)? (ws_size - moff) : 0;
  long long chl = (long long)(avail / ((size_t)NREL*HID*4));
  int CH = (int)(chl > NUSERS ? NUSERS : chl);
  CH &= ~63;
  if(CH < 64) CH = 64;  // if ws is this small nothing fits anyway
  float* Mbuf = (float*)(ws + moff);

  // ---- CSR build (shared by both layers) ----
  hipMemsetAsync(cnt_item, 0, (size_t)NITEMS*NREL*4, stream);
  hipMemsetAsync(cnt_user, 0, (size_t)NUSERS*NREL*4, stream);
  int eb = (E+255)/256;
  count_edges_k<<<eb,256,0,stream>>>(src,dst,et,E,cnt_item,cnt_user);

  int nbI = (NITEMS+1023)/1024, nbU = (NUSERS+1023)/1024;
  scan_s1<<<nbI,256,0,stream>>>(cnt_item, NITEMS, btot);
  scan_s2<<<1,1024,0,stream>>>(btot, nbI, boff, off_item+NITEMS);
  scan_s3<<<nbI,256,0,stream>>>(cnt_item, NITEMS, boff, off_item);
  scan_s1<<<nbU,256,0,stream>>>(cnt_user, NUSERS, btot);
  scan_s2<<<1,1024,0,stream>>>(btot, nbU, boff, off_user+NUSERS);
  scan_s3<<<nbU,256,0,stream>>>(cnt_user, NUSERS, boff, off_user);

  copy_int_k<<<(NITEMS+255)/256,256,0,stream>>>(off_item, cur_item, NITEMS);
  copy_int_k<<<(NUSERS+255)/256,256,0,stream>>>(off_user, cur_user, NUSERS);
  scatter_k<<<eb,256,0,stream>>>(src,dst,et,E,cur_item,cur_user,adj_item,adj_user);

  // ---- layer 1 ----
  gemm_k<HID,8,true><<<(NITEMS+63)/64,256,0,stream>>>(x_item, UDIM, root1_ui, item1, HID, b1_ui, NITEMS, UDIM);
  gemm_k<HID,8,true><<<(NUSERS+63)/64,256,0,stream>>>(x_user, UDIM, root1_iu, user1, HID, b1_iu, NUSERS, UDIM);

  for(int lo=0; lo<NITEMS; lo+=CH){
    int cn = imin(CH, NITEMS-lo);
    agg_k<UDIM><<<(cn+3)/4,256,0,stream>>>(x_user, adj_item, off_item, cnt_item, Mbuf, lo, cn);
    gemm_k<HID,8,false><<<(cn+63)/64,256,0,stream>>>(Mbuf, NREL*UDIM, W1_ui, item1+(size_t)lo*HID, HID, nullptr, cn, NREL*UDIM);
  }
  for(int lo=0; lo<NUSERS; lo+=CH){
    int cn = imin(CH, NUSERS-lo);
    agg_k<UDIM><<<(cn+3)/4,256,0,stream>>>(x_item, adj_user, off_user, cnt_user, Mbuf, lo, cn);
    gemm_k<HID,8,false><<<(cn+63)/64,256,0,stream>>>(Mbuf, NREL*UDIM, W1_iu, user1+(size_t)lo*HID, HID, nullptr, cn, NREL*UDIM);
  }
  relu_k<<<2048,256,0,stream>>>(user1, (size_t)NUSERS*HID + (size_t)NITEMS*HID); // user1,item1 contiguous

  // ---- layer 2 ----
  float* user2 = out;
  float* item2 = out + (size_t)NUSERS*ODIM;
  gemm_k<ODIM,4,true><<<(NUSERS+63)/64,256,0,stream>>>(user1, HID, root2_iu, user2, ODIM, b2_iu, NUSERS, HID);
  gemm_k<ODIM,4,true><<<(NITEMS+63)/64,256,0,stream>>>(item1, HID, root2_ui, item2, ODIM, b2_ui, NITEMS, HID);

  for(int lo=0; lo<NITEMS; lo+=CH){
    int cn = imin(CH, NITEMS-lo);
    agg_k<HID><<<(cn+3)/4,256,0,stream>>>(user1, adj_item, off_item, cnt_item, Mbuf, lo, cn);
    gemm_k<ODIM,4,false><<<(cn+63)/64,256,0,stream>>>(Mbuf, NREL*HID, W2_ui, item2+(size_t)lo*ODIM, ODIM, nullptr, cn, NREL*HID);
  }
  for(int lo=0; lo<NUSERS; lo+=CH){
    int cn = imin(CH, NUSERS-lo);
    agg_k<HID><<<(cn+3)/4,256,0,stream>>>(item1, adj_user, off_user, cnt_user, Mbuf, lo, cn);
    gemm_k<ODIM,4,false><<<(cn+63)/64,256,0,stream>>>(Mbuf, NREL*HID, W2_iu, user2+(size_t)lo*ODIM, ODIM, nullptr, cn, NREL*HID);
  }
}

// Round 2
// 746.027 us; speedup vs baseline: 2.4365x; 2.4365x over previous
//
#include <hip/hip_runtime.h>
#include <hip/hip_bf16.h>
#include <cstdint>
#include <cstddef>

#define NUSERS 200000
#define NITEMS 100000
#define UDIM 64
#define HID 128
#define ODIM 64
#define NREL 5

typedef unsigned short ushortT;
typedef __bf16 bf16x8 __attribute__((ext_vector_type(8)));
typedef float f32x4 __attribute__((ext_vector_type(4)));

static inline size_t align256(size_t x){ return (x + 255) & ~(size_t)255; }
static inline int imin(int a,int b){ return a<b?a:b; }

__device__ __forceinline__ unsigned short f2bf(float f){
  unsigned int u = __builtin_bit_cast(unsigned int, f);
  unsigned int r = (u + 0x7fffu + ((u>>16)&1u)) >> 16;   // RNE
  return (unsigned short)r;
}
__device__ __forceinline__ float b2f(unsigned short u){
  return __builtin_bit_cast(float, ((unsigned int)u)<<16);
}
__device__ __forceinline__ void gld_lds16(const void* g, void* s){
  __builtin_amdgcn_global_load_lds((const __attribute__((address_space(1))) void*)g,
                                   (__attribute__((address_space(3))) void*)s, 16, 0, 0);
}

// ---------------- CSR build ----------------

__global__ void count_edges_k(const int* __restrict__ src, const int* __restrict__ dst,
                              const int* __restrict__ et, int E,
                              int* __restrict__ cnt_item, int* __restrict__ cnt_user){
  int e = blockIdx.x*blockDim.x + threadIdx.x;
  if(e < E){
    int t = et[e];
    atomicAdd(&cnt_item[dst[e]*NREL + t], 1);
    atomicAdd(&cnt_user[src[e]*NREL + t], 1);
  }
}

__global__ __launch_bounds__(256) void scan_s1(const int* __restrict__ cnt5, int n, int* __restrict__ btot){
  int t = threadIdx.x;
  int base = blockIdx.x*1024 + t*4;
  int s = 0;
  #pragma unroll
  for(int j=0;j<4;++j){
    int i = base + j;
    if(i < n){ const int* c = &cnt5[i*NREL]; s += c[0]+c[1]+c[2]+c[3]+c[4]; }
  }
  __shared__ int red[256];
  red[t] = s; __syncthreads();
  for(int o=128;o>0;o>>=1){ if(t<o) red[t]+=red[t+o]; __syncthreads(); }
  if(t==0) btot[blockIdx.x] = red[0];
}

__global__ __launch_bounds__(1024) void scan_s2(const int* __restrict__ btot, int nb,
                                                int* __restrict__ boff, int* __restrict__ total_out){
  __shared__ int sh[1024];
  int t = threadIdx.x;
  int v = (t<nb)? btot[t] : 0;
  sh[t] = v; __syncthreads();
  for(int o=1;o<1024;o<<=1){
    int add = (t>=o)? sh[t-o] : 0;
    __syncthreads();
    sh[t] += add;
    __syncthreads();
  }
  if(t<nb) boff[t] = sh[t]-v;
  if(t==1023) *total_out = sh[1023];
}

__global__ __launch_bounds__(256) void scan_s3(const int* __restrict__ cnt5, int n,
                                               const int* __restrict__ boff, int* __restrict__ off){
  int t = threadIdx.x, b = blockIdx.x;
  int base = b*1024 + t*4;
  int pre[4]; int s = 0;
  #pragma unroll
  for(int j=0;j<4;++j){
    int i = base + j; int d = 0;
    if(i < n){ const int* c = &cnt5[i*NREL]; d = c[0]+c[1]+c[2]+c[3]+c[4]; }
    pre[j] = s; s += d;
  }
  __shared__ int sh[256];
  sh[t] = s; __syncthreads();
  int inc = s;
  for(int o=1;o<256;o<<=1){
    int add = (t>=o)? sh[t-o] : 0;
    __syncthreads();
    sh[t] += add;
    __syncthreads();
  }
  int texcl = sh[t] - inc;
  int bo = boff[b];
  #pragma unroll
  for(int j=0;j<4;++j){
    int i = base + j;
    if(i < n) off[i] = bo + texcl + pre[j];
  }
}

__global__ void copy_int_k(const int* __restrict__ a, int* __restrict__ b, int n){
  int i = blockIdx.x*blockDim.x + threadIdx.x;
  if(i < n) b[i] = a[i];
}

__global__ void scatter_k(const int* __restrict__ src, const int* __restrict__ dst,
                          const int* __restrict__ et, int E,
                          int* __restrict__ cur_item, int* __restrict__ cur_user,
                          int* __restrict__ adj_item, int* __restrict__ adj_user){
  int e = blockIdx.x*blockDim.x + threadIdx.x;
  if(e < E){
    int s = src[e], d = dst[e], t = et[e];
    int p1 = atomicAdd(&cur_item[d], 1);
    adj_item[p1] = (s<<3) | t;
    int p2 = atomicAdd(&cur_user[s], 1);
    adj_user[p2] = (d<<3) | t;
  }
}

// ---------------- fp32 -> bf16 conversions ----------------

__global__ void f2bf4_k(const float4* __restrict__ a, uint2* __restrict__ b, int n4){
  int i = blockIdx.x*blockDim.x + threadIdx.x;
  if(i < n4){
    float4 v = a[i];
    uint2 o;
    o.x = (unsigned)f2bf(v.x) | ((unsigned)f2bf(v.y)<<16);
    o.y = (unsigned)f2bf(v.z) | ((unsigned)f2bf(v.w)<<16);
    b[i] = o;
  }
}

// Build BT[Dout][6*Din] bf16 = [root; W_0..W_4]^T
__global__ void prep_bt_k(const float* __restrict__ root, const float* __restrict__ W,
                          ushortT* __restrict__ BT, int Din, int Dout){
  int K = 6*Din;
  int idx = blockIdx.x*blockDim.x + threadIdx.x;
  if(idx >= Dout*K) return;
  int n = idx / K, k = idx % K;
  float v = (k < Din) ? root[(size_t)k*Dout + n] : W[(size_t)(k-Din)*Dout + n];
  BT[idx] = f2bf(v);
}

// ---------------- aggregation (wave per node) ----------------
// Mbuf row (6*D bf16) = [ x_dst[node] | mean_r0 | ... | mean_r4 ]

template<int D>
__global__ __launch_bounds__(256) void agg_bf_k(const ushortT* __restrict__ xsrc,
    const ushortT* __restrict__ xdst, const int* __restrict__ adj,
    const int* __restrict__ off, const int* __restrict__ cnt5,
    ushortT* __restrict__ Mbuf, int lo, int cn)
{
  int wid  = (int)((blockIdx.x*(size_t)blockDim.x + threadIdx.x) >> 6);
  int lane = threadIdx.x & 63;
  if(wid >= cn) return;
  int node = lo + wid;
  int e0 = off[node], e1 = off[node+1];
  constexpr int V = D/64;   // bf16 per lane
  float sum[NREL][V];
  #pragma unroll
  for(int r=0;r<NREL;++r)
    #pragma unroll
    for(int v=0;v<V;++v) sum[r][v] = 0.f;
  for(int e=e0; e<e1; ++e){
    int a = adj[e];
    int p = a >> 3, t = a & 7;
    const ushortT* xp = xsrc + (size_t)p*D + lane*V;
    float v0, v1 = 0.f;
    if(V==2){ unsigned u = *(const unsigned*)xp; v0 = b2f((unsigned short)(u&0xffff)); v1 = b2f((unsigned short)(u>>16)); }
    else    { v0 = b2f(*xp); }
    #pragma unroll
    for(int r=0;r<NREL;++r){
      if(t==r){ sum[r][0] += v0; if(V==2) sum[r][1] += v1; }
    }
  }
  ushortT* mp = Mbuf + (size_t)wid*(6*D);
  { // copy dst features into cols [0,D)
    const ushortT* dp = xdst + (size_t)node*D + lane*V;
    if(V==2) *(unsigned*)(mp + lane*2) = *(const unsigned*)dp;
    else     mp[lane] = *dp;
  }
  #pragma unroll
  for(int r=0;r<NREL;++r){
    int c = cnt5[node*NREL + r];
    float sc = 1.f/(float)(c>0?c:1);
    mp[D + r*D + lane*V] = f2bf(sum[r][0]*sc);
    if(V==2) mp[D + r*D + lane*V + 1] = f2bf(sum[r][1]*sc);
  }
}

// ---------------- bf16 MFMA GEMM: C[M][BN] = A[M][K] @ BT[BN][K]^T + bias ----------------
// A row-major bf16, BT row-major bf16 (i.e. B transposed). grid.x = ceil(M/128).
// OUTBF: C is bf16 with relu;  else C is fp32.

template<int BN, bool OUTBF>
__global__ __launch_bounds__(256) void mfma_gemm_k(
    const ushortT* __restrict__ A, const ushortT* __restrict__ BT,
    const float* __restrict__ bias, void* __restrict__ Cv, int M, int K)
{
  constexpr int BM = 128, BK = 64;
  constexpr int WCN   = (BN==128)? 2 : 1;   // waves along cols
  constexpr int FR    = (BN==128)? 4 : 2;   // 16-row frags per wave
  constexpr int WROWS = FR*16;
  constexpr int FC    = 4;                  // 64 cols per wave
  __shared__ alignas(16) unsigned char sA[BM*128];   // [row][128B], swizzled
  __shared__ alignas(16) unsigned char sB[BN*128];

  const int tid = threadIdx.x;
  const int w = tid >> 6, l = tid & 63;
  const int wr = w / WCN, wc = w % WCN;
  const int row0 = blockIdx.x * BM;

  f32x4 acc[FR][FC];
  #pragma unroll
  for(int i=0;i<FR;++i)
    #pragma unroll
    for(int j=0;j<FC;++j) acc[i][j] = (f32x4){0.f,0.f,0.f,0.f};

  const int lr  = l >> 3;          // staging: row within 8-row group
  const int lc  = (l & 7) * 16;    // staging: byte col within 128B row

  for(int k0=0; k0<K; k0+=BK){
    // stage A tile [128][BK] (each wave: 4 x 1KB loads, 8 rows each)
    #pragma unroll
    for(int j=0;j<4;++j){
      int r = w*32 + j*8 + lr;
      int grow = row0 + r; grow = (grow < M) ? grow : (M-1);
      const unsigned char* g = (const unsigned char*)(A + (size_t)grow*K + k0) + (lc ^ ((r&7)<<4));
      gld_lds16(g, sA + (w*32 + j*8)*128);
    }
    // stage B tile [BN][BK]
    #pragma unroll
    for(int j=0;j<BN/32;++j){
      int r = w*(BN/4) + j*8 + lr;
      const unsigned char* g = (const unsigned char*)(BT + (size_t)r*K + k0) + (lc ^ ((r&7)<<4));
      gld_lds16(g, sB + (w*(BN/4) + j*8)*128);
    }
    __syncthreads();
    #pragma unroll
    for(int kk=0;kk<2;++kk){
      const int cb = kk*64 + (l>>4)*16;
      bf16x8 af[FR], bfr[FC];
      #pragma unroll
      for(int i=0;i<FR;++i){
        int r = wr*WROWS + i*16 + (l&15);
        af[i] = *reinterpret_cast<const bf16x8*>(sA + r*128 + (cb ^ ((r&7)<<4)));
      }
      #pragma unroll
      for(int j=0;j<FC;++j){
        int c = wc*64 + j*16 + (l&15);
        bfr[j] = *reinterpret_cast<const bf16x8*>(sB + c*128 + (cb ^ ((c&7)<<4)));
      }
      #pragma unroll
      for(int i=0;i<FR;++i)
        #pragma unroll
        for(int j=0;j<FC;++j)
          acc[i][j] = __builtin_amdgcn_mfma_f32_16x16x32_bf16(af[i], bfr[j], acc[i][j], 0, 0, 0);
    }
    __syncthreads();
  }
  // epilogue: D mapping col=lane&15, row=(lane>>4)*4+reg
  #pragma unroll
  for(int i=0;i<FR;++i){
    #pragma unroll
    for(int rr=0;rr<4;++rr){
      int grow = row0 + wr*WROWS + i*16 + (l>>4)*4 + rr;
      if(grow >= M) continue;
      #pragma unroll
      for(int j=0;j<FC;++j){
        int col = wc*64 + j*16 + (l&15);
        float v = acc[i][j][rr] + bias[col];
        if(OUTBF){
          v = fmaxf(v, 0.f);
          ((ushortT*)Cv)[(size_t)grow*BN + col] = f2bf(v);
        } else {
          ((float*)Cv)[(size_t)grow*BN + col] = v;
        }
      }
    }
  }
}

// ---------------- host ----------------

extern "C" void kernel_launch(void* const* d_in, const int* in_sizes, int n_in,
                              void* d_out, int out_size, void* d_ws, size_t ws_size,
                              hipStream_t stream){
  const float* x_user   = (const float*)d_in[0];
  const float* x_item   = (const float*)d_in[1];
  const int*   ei       = (const int*)d_in[2];
  const int*   et       = (const int*)d_in[3];
  const float* W1_ui    = (const float*)d_in[4];
  const float* root1_ui = (const float*)d_in[5];
  const float* b1_ui    = (const float*)d_in[6];
  const float* W1_iu    = (const float*)d_in[7];
  const float* root1_iu = (const float*)d_in[8];
  const float* b1_iu    = (const float*)d_in[9];
  const float* W2_ui    = (const float*)d_in[10];
  const float* root2_ui = (const float*)d_in[11];
  const float* b2_ui    = (const float*)d_in[12];
  const float* W2_iu    = (const float*)d_in[13];
  const float* root2_iu = (const float*)d_in[14];
  const float* b2_iu    = (const float*)d_in[15];
  const int E = in_sizes[3];
  const int* src = ei;
  const int* dst = ei + E;
  float* out = (float*)d_out;

  uint8_t* ws = (uint8_t*)d_ws;
  size_t o = 0;
  auto alloc = [&](size_t bytes){ size_t r = o; o = align256(o + bytes); return r; };
  int* cnt_item = (int*)(ws + alloc((size_t)NITEMS*NREL*4));
  int* cnt_user = (int*)(ws + alloc((size_t)NUSERS*NREL*4));
  int* off_item = (int*)(ws + alloc((size_t)(NITEMS+1)*4));
  int* off_user = (int*)(ws + alloc((size_t)(NUSERS+1)*4));
  int* cur_item = (int*)(ws + alloc((size_t)NITEMS*4));
  int* cur_user = (int*)(ws + alloc((size_t)NUSERS*4));
  int* adj_item = (int*)(ws + alloc((size_t)E*4));
  int* adj_user = (int*)(ws + alloc((size_t)E*4));
  int* btot     = (int*)(ws + alloc(1024*4));
  int* boff     = (int*)(ws + alloc(1024*4));
  ushortT* xu_bf = (ushortT*)(ws + alloc((size_t)NUSERS*UDIM*2));
  ushortT* xi_bf = (ushortT*)(ws + alloc((size_t)NITEMS*UDIM*2));
  ushortT* h1u   = (ushortT*)(ws + alloc((size_t)NUSERS*HID*2));
  ushortT* h1i   = (ushortT*)(ws + alloc((size_t)NITEMS*HID*2));
  ushortT* BT1ui = (ushortT*)(ws + alloc((size_t)HID*(6*UDIM)*2));
  ushortT* BT1iu = (ushortT*)(ws + alloc((size_t)HID*(6*UDIM)*2));
  ushortT* BT2ui = (ushortT*)(ws + alloc((size_t)ODIM*(6*HID)*2));
  ushortT* BT2iu = (ushortT*)(ws + alloc((size_t)ODIM*(6*HID)*2));
  size_t moff = o;
  size_t avail = (ws_size > moff)? (ws_size - moff) : 0;
  ushortT* Mbuf = (ushortT*)(ws + moff);
  long long c1 = (long long)(avail / ((size_t)6*UDIM*2));
  long long c2 = (long long)(avail / ((size_t)6*HID*2));
  int CH1 = (int)(c1 > NUSERS ? NUSERS : c1); CH1 &= ~127; if(CH1 < 128) CH1 = 128;
  int CH2 = (int)(c2 > NUSERS ? NUSERS : c2); CH2 &= ~127; if(CH2 < 128) CH2 = 128;

  // ---- CSR build (shared by both layers) ----
  hipMemsetAsync(cnt_item, 0, (size_t)NITEMS*NREL*4, stream);
  hipMemsetAsync(cnt_user, 0, (size_t)NUSERS*NREL*4, stream);
  int eb = (E+255)/256;
  count_edges_k<<<eb,256,0,stream>>>(src,dst,et,E,cnt_item,cnt_user);

  int nbI = (NITEMS+1023)/1024, nbU = (NUSERS+1023)/1024;
  scan_s1<<<nbI,256,0,stream>>>(cnt_item, NITEMS, btot);
  scan_s2<<<1,1024,0,stream>>>(btot, nbI, boff, off_item+NITEMS);
  scan_s3<<<nbI,256,0,stream>>>(cnt_item, NITEMS, boff, off_item);
  scan_s1<<<nbU,256,0,stream>>>(cnt_user, NUSERS, btot);
  scan_s2<<<1,1024,0,stream>>>(btot, nbU, boff, off_user+NUSERS);
  scan_s3<<<nbU,256,0,stream>>>(cnt_user, NUSERS, boff, off_user);

  copy_int_k<<<(NITEMS+255)/256,256,0,stream>>>(off_item, cur_item, NITEMS);
  copy_int_k<<<(NUSERS+255)/256,256,0,stream>>>(off_user, cur_user, NUSERS);
  scatter_k<<<eb,256,0,stream>>>(src,dst,et,E,cur_item,cur_user,adj_item,adj_user);

  // ---- dtype prep ----
  {
    int n4 = NUSERS*UDIM/4;
    f2bf4_k<<<(n4+255)/256,256,0,stream>>>((const float4*)x_user, (uint2*)xu_bf, n4);
    n4 = NITEMS*UDIM/4;
    f2bf4_k<<<(n4+255)/256,256,0,stream>>>((const float4*)x_item, (uint2*)xi_bf, n4);
  }
  prep_bt_k<<<(HID*6*UDIM+255)/256,256,0,stream>>>(root1_ui, W1_ui, BT1ui, UDIM, HID);
  prep_bt_k<<<(HID*6*UDIM+255)/256,256,0,stream>>>(root1_iu, W1_iu, BT1iu, UDIM, HID);
  prep_bt_k<<<(ODIM*6*HID+255)/256,256,0,stream>>>(root2_ui, W2_ui, BT2ui, HID, ODIM);
  prep_bt_k<<<(ODIM*6*HID+255)/256,256,0,stream>>>(root2_iu, W2_iu, BT2iu, HID, ODIM);

  // ---- layer 1 ----
  for(int lo=0; lo<NITEMS; lo+=CH1){
    int cn = imin(CH1, NITEMS-lo);
    agg_bf_k<UDIM><<<(cn+3)/4,256,0,stream>>>(xu_bf, xi_bf, adj_item, off_item, cnt_item, Mbuf, lo, cn);
    mfma_gemm_k<HID,true><<<(cn+127)/128,256,0,stream>>>(Mbuf, BT1ui, b1_ui, h1i + (size_t)lo*HID, cn, 6*UDIM);
  }
  for(int lo=0; lo<NUSERS; lo+=CH1){
    int cn = imin(CH1, NUSERS-lo);
    agg_bf_k<UDIM><<<(cn+3)/4,256,0,stream>>>(xi_bf, xu_bf, adj_user, off_user, cnt_user, Mbuf, lo, cn);
    mfma_gemm_k<HID,true><<<(cn+127)/128,256,0,stream>>>(Mbuf, BT1iu, b1_iu, h1u + (size_t)lo*HID, cn, 6*UDIM);
  }

  // ---- layer 2 ----
  float* user2 = out;
  float* item2 = out + (size_t)NUSERS*ODIM;
  for(int lo=0; lo<NITEMS; lo+=CH2){
    int cn = imin(CH2, NITEMS-lo);
    agg_bf_k<HID><<<(cn+3)/4,256,0,stream>>>(h1u, h1i, adj_item, off_item, cnt_item, Mbuf, lo, cn);
    mfma_gemm_k<ODIM,false><<<(cn+127)/128,256,0,stream>>>(Mbuf, BT2ui, b2_ui, item2 + (size_t)lo*ODIM, cn, 6*HID);
  }
  for(int lo=0; lo<NUSERS; lo+=CH2){
    int cn = imin(CH2, NUSERS-lo);
    agg_bf_k<HID><<<(cn+3)/4,256,0,stream>>>(h1i, h1u, adj_user, off_user, cnt_user, Mbuf, lo, cn);
    mfma_gemm_k<ODIM,false><<<(cn+127)/128,256,0,stream>>>(Mbuf, BT2iu, b2_iu, user2 + (size_t)lo*ODIM, cn, 6*HID);
  }
}